// Round 22
// baseline (11892.963 us; speedup 1.0000x reference)
//
#include <hip/hip_runtime.h>
#include <cstdint>
#include <cstddef>
#include <cmath>

// DTS-SNN forward, v22 = v21 numerics (PASSED, absmax 0.01367188), fused:
//  - snn_input:  unchanged v20 input (all t, one launch) -> sbits[t][iw][b]
//  - snn_tr:     bit-transpose -> sbT[t][wv][i] = 64-bit mask over b-lanes
//  - snn_hidden: ONE launch, grid 1024 (h): weights in LDS once, c_h/m_h in
//                registers across t, inner loop = v_cndmask(SGPR-pair mask)
//                + v_add (2 VALU/elem); s_h emitted as ballot bitmasks.
//  - snn_outdot: all (t,b,o) output dots from s_h bits (smear+and+add,
//                bit-exact vs fmaf(s,w,acc) for s in {0,1})
//  - snn_outrec: c_o/m_o/ssum recurrence in registers, writes out (+bias).
// Chain orders (ascending-k single-accumulator) byte-identical to v17-v21.
// d_ws: sbits u64[100][51][256] @0, sbT u64[100][4][3264] @10444800,
//       sbh u64[100][1024][4] @20889600, dto f32[100][256][20] @24166400.

#define TSTEPS 100
#define BATCHN 256
#define CCH    768
#define GRP    192
#define NIN    3264
#define NHID   1024
#define NOUT   20
#define NW     51        // 3264 / 64 bit-words

#define OFF_SBITS_B 0
#define OFF_SBT_B   10444800
#define OFF_SBH_B   20889600
#define OFF_DTO_B   24166400

#define OUT_BIAS (+0.005f)

__device__ __forceinline__ float v22_spike(float m) {
    return (m - 0.3f) > 0.0f ? 1.0f : 0.0f;
}

// Correctly-rounded f32 of exp(f32(-dt/tau)).
__device__ __forceinline__ float v22_dm() { return (float)exp((double)(float)(-1.0/20.0)); }
__device__ __forceinline__ float v22_d2() { return (float)exp((double)(float)(-1.0/60.0)); }
__device__ __forceinline__ float v22_ds() { return (float)exp((double)(float)(-1.0/5.0)); }

// bit k of x smeared to 0 / 0xFFFFFFFF (compiles to v_bfe_i32)
#define BIT_SMEAR(x, k) (((int)((unsigned)(x) << (31 - (k)))) >> 31)

// ---------------- input kernel: ALL timesteps, one launch -----------------
// grid 256 (b), block 256 (lanes = c/i). Identical arithmetic to v20.
__global__ __launch_bounds__(256) void snn_input_v22(
    const float* __restrict__ events, const float* __restrict__ w_enc,
    unsigned long long* __restrict__ sbits_all)
{
#pragma clang fp contract(off)
    const int b = blockIdx.x, tid = threadIdx.x;
    const float DTR1 = v22_dm(), DTR2 = v22_d2();
    const float DMEM = v22_dm();
    __shared__ float surf[CCH + 16];        // zero-padded, [8..775] live

    if (tid < 8) surf[tid] = 0.0f;
    if (tid >= 248) surf[tid + 528] = 0.0f; // 776..783
    const float we0 = w_enc[0], we1 = w_enc[1], we2 = w_enc[2], we3 = w_enc[3];

    float tr1[3] = {0.0f, 0.0f, 0.0f};
    float tr2[3] = {0.0f, 0.0f, 0.0f};
    float m_in[13];
#pragma unroll
    for (int k = 0; k < 13; ++k) m_in[k] = 0.0f;

    for (int t = 0; t < TSTEPS; ++t) {
#pragma unroll
        for (int k = 0; k < 3; ++k) {
            int c = tid + k * 256;
            float e = events[((size_t)b * TSTEPS + t) * CCH + c];
            e = fminf(fmaxf(e, 0.0f), 1.0f);
            float t1 = tr1[k] * DTR1 + e;    // mul, add (no fuse)
            float t2 = tr2[k] * DTR2 + e;
            tr1[k] = t1; tr2[k] = t2;
            surf[8 + c] = (t1 - t2) * 0.5f;
        }
        __syncthreads();
#pragma unroll
        for (int k = 0; k < 13; ++k) {
            int i = tid + k * 256;
            bool spike = false;
            bool act = (i < NIN);
            if (act) {
                int r = i / GRP, g = i - r * GRP;    // i = r*G + g
                int base = g * 4 + r;
                float enc = ((we0 * surf[base] + we1 * surf[base + 1])
                             + we2 * surf[base + 2]) + we3 * surf[base + 3];
                float m = m_in[k];
                float spp = v22_spike(m);            // s_in(t-1)
                m = m * DMEM * (1.0f - spp) + enc;   // op-by-op
                m_in[k] = m;
                spike = (m - 0.3f) > 0.0f;
            }
            unsigned long long ball = __ballot(spike);
            if (((tid & 63) == 0) && act) {
                int iw = (tid >> 6) + 4 * k;
                sbits_all[((size_t)t * NW + iw) * BATCHN + b] = ball;
            }
        }
        __syncthreads();                     // WAR on surf before next t
    }
}

// ---------------- bit transpose: sbits[t][iw][b] -> sbT[t][wv][i] ---------
// grid 100 (t), block 256 (lanes = b). sbT[t][wv][i] bit l = spike(i, b=wv*64+l).
__global__ __launch_bounds__(256) void snn_tr_v22(
    const unsigned long long* __restrict__ sbits_all,
    unsigned long long* __restrict__ sbT)
{
    const int t = blockIdx.x, tid = threadIdx.x;
    const int wv = tid >> 6;
    const bool lead = (tid & 63) == 0;
    unsigned long long* o = sbT + ((size_t)t * 4 + wv) * NIN;

    for (int iw = 0; iw < NW; ++iw) {
        unsigned long long m = sbits_all[((size_t)t * NW + iw) * BATCHN + tid];
        unsigned lo = (unsigned)m, hi = (unsigned)(m >> 32);
#pragma unroll
        for (int j = 0; j < 32; ++j) {
            unsigned long long bl = __ballot((lo >> j) & 1u);
            if (lead) o[iw * 64 + j] = bl;
        }
#pragma unroll
        for (int j = 0; j < 32; ++j) {
            unsigned long long bl = __ballot((hi >> j) & 1u);
            if (lead) o[iw * 64 + 32 + j] = bl;
        }
    }
}

// ---------------- hidden kernel: ALL timesteps, one launch ----------------
// grid 1024 (h), block 256 (b). Weights in LDS (once), c_h/m_h in regs.
// Inner: s_load mask (SGPR pair) -> v_cndmask_b32 + v_add = 2 VALU/elem.
// Chain (ascending i, single acc) bit-identical to v20/v21 (+0 adds).
__global__ __launch_bounds__(256) void snn_hidden_v22(
    const unsigned long long* __restrict__ sbT,
    const float* __restrict__ w_hid,
    unsigned long long* __restrict__ sbh)
{
#pragma clang fp contract(off)
    const int h = blockIdx.x, tid = threadIdx.x;
    const float DMEM = v22_dm(), DSYN = v22_ds();
    const int wvu = __builtin_amdgcn_readfirstlane(tid >> 6);  // wave-uniform
    __shared__ float4 wlds[NIN / 4];         // 13056 B

    const float4* __restrict__ w4 = (const float4*)(w_hid + (size_t)h * NIN);
    for (int q = tid; q < NIN / 4; q += 256) wlds[q] = w4[q];
    __syncthreads();

    float c_h = 0.0f, m_h = 0.0f;

    for (int t = 0; t < TSTEPS; ++t) {
        const unsigned long long* __restrict__ mrow =
            sbT + ((size_t)t * 4 + wvu) * NIN;           // uniform -> s_load
        float acc = 0.0f;
        for (int i0 = 0; i0 < NIN; i0 += 4) {
            float4 wq = wlds[i0 >> 2];                   // ds_read_b128 bcast
            unsigned long long m0 = mrow[i0 + 0];
            unsigned long long m1 = mrow[i0 + 1];
            unsigned long long m2 = mrow[i0 + 2];
            unsigned long long m3 = mrow[i0 + 3];
            float s0, s1, s2, s3;
            asm("v_cndmask_b32 %0, 0, %1, %2" : "=v"(s0) : "v"(wq.x), "s"(m0));
            acc = acc + s0;
            asm("v_cndmask_b32 %0, 0, %1, %2" : "=v"(s1) : "v"(wq.y), "s"(m1));
            acc = acc + s1;
            asm("v_cndmask_b32 %0, 0, %1, %2" : "=v"(s2) : "v"(wq.z), "s"(m2));
            acc = acc + s2;
            asm("v_cndmask_b32 %0, 0, %1, %2" : "=v"(s3) : "v"(wq.w), "s"(m3));
            acc = acc + s3;
        }
        float cc = c_h * DSYN + acc;             // 2 ops (c_h reg == old st)
        float shp = v22_spike(m_h);              // s_h(t-1)
        m_h = m_h * DMEM * (1.0f - shp) + cc;    // op-by-op
        c_h = cc;
        unsigned long long sb = __ballot((m_h - 0.3f) > 0.0f);
        if ((tid & 63) == 0)
            sbh[((size_t)t * NHID + h) * 4 + wvu] = sb;
    }
}

// ---------------- output dots: all (t,b,o), one launch --------------------
// grid 3200 (= 100 t x 32), block 256: b = idx*8 + tid/32, o = tid%32.
// dot over ascending h from s_h bits; smear+and+add == fmaf(s,w,acc).
__global__ __launch_bounds__(256) void snn_outdot_v22(
    const unsigned long long* __restrict__ sbh,
    const float* __restrict__ w_out, float* __restrict__ dto)
{
#pragma clang fp contract(off)
    const int t = blockIdx.x >> 5, idx = blockIdx.x & 31;
    const int b = idx * 8 + (threadIdx.x >> 5), o = threadIdx.x & 31;
    if (o >= NOUT) return;
    const unsigned* __restrict__ sb32 =
        (const unsigned*)(sbh + (size_t)t * NHID * 4);
    const int wsel = b >> 5, kk = b & 31;        // u32 word + bit within
    const float* __restrict__ wr = w_out + (size_t)o * NHID;
    float acc = 0.0f;
    for (int h = 0; h < NHID; ++h) {
        unsigned wb = sb32[h * 8 + wsel];
        int sm = BIT_SMEAR(wb, kk);
        acc = acc + __int_as_float(sm & __float_as_int(wr[h]));
    }
    dto[((size_t)t * BATCHN + b) * NOUT + o] = acc;
}

// ---------------- output recurrence: registers, one launch ----------------
// grid 20 (o), block 256 (b). Same op order per (b,o) over t as v21 tail.
__global__ __launch_bounds__(256) void snn_outrec_v22(
    const float* __restrict__ dto, float* __restrict__ out)
{
#pragma clang fp contract(off)
    const int o = blockIdx.x, b = threadIdx.x;
    const float DMEM = v22_dm(), DSYN = v22_ds();
    float co = 0.0f, mo = 0.0f, ss = 0.0f;
    for (int t = 0; t < TSTEPS; ++t) {
        float d = dto[((size_t)t * BATCHN + b) * NOUT + o];
        float c2 = co * DSYN + d;                // 2 ops
        float sop = v22_spike(mo);               // s_o(t-1)
        mo = mo * DMEM * (1.0f - sop) + c2;      // op-by-op
        co = c2;
        ss = ss + v22_spike(mo);
    }
    out[b * NOUT + o] = ss / 100.0f + OUT_BIAS;
}

extern "C" void kernel_launch(void* const* d_in, const int* in_sizes, int n_in,
                              void* d_out, int out_size, void* d_ws, size_t ws_size,
                              hipStream_t stream) {
    const float* events = (const float*)d_in[0];
    const float* w_enc  = (const float*)d_in[1];
    const float* w_hid  = (const float*)d_in[2];
    const float* w_out  = (const float*)d_in[3];
    char* ws = (char*)d_ws;
    unsigned long long* sbits = (unsigned long long*)(ws + OFF_SBITS_B);
    unsigned long long* sbT   = (unsigned long long*)(ws + OFF_SBT_B);
    unsigned long long* sbh   = (unsigned long long*)(ws + OFF_SBH_B);
    float*              dto   = (float*)(ws + OFF_DTO_B);
    float* out = (float*)d_out;

    // all buffers fully written before read -> no memset needed
    snn_input_v22<<<256, 256, 0, stream>>>(events, w_enc, sbits);
    snn_tr_v22<<<100, 256, 0, stream>>>(sbits, sbT);
    snn_hidden_v22<<<NHID, 256, 0, stream>>>(sbT, w_hid, sbh);
    snn_outdot_v22<<<3200, 256, 0, stream>>>(sbh, w_out, dto);
    snn_outrec_v22<<<NOUT, 256, 0, stream>>>(dto, out);
}

// Round 23
// 5388.638 us; speedup vs baseline: 2.2070x; 2.2070x over previous
//
#include <hip/hip_runtime.h>
#include <cstdint>
#include <cstddef>
#include <cmath>

// DTS-SNN forward, v23 = v20 numerics (PASSED, absmax 0.01367188), fused:
//  - snn_input:  v20/v22 input (all t, one launch) -> sbits[t][iw][b]
//  - snn_hidden: ONE launch, grid 512 (h-PAIR) x block 256 (b):
//      * both weight rows staged in LDS once (26 KB), float4 broadcast reads
//      * masks per-lane vector loads (v19-proven path), one-word prefetch
//      * smear shared across the 2 h: 2.5 VALU/h-elem (was 3)
//      * c_h/m_h in registers across t; s_h emitted as ballot bitmasks
//      * per-h chain: ascending i, single f32 acc, smear+and+add — the
//        bit-exact-vs-fmaf identity verified on HW in v20/v21
//  - snn_outdot/outrec: unchanged from v22 (passed).
// ws: sbits u64[100][51][256] @0, sbh u64[100][1024][4] @10444800,
//     dto f32[100][256][20] @13721600.

#define TSTEPS 100
#define BATCHN 256
#define CCH    768
#define GRP    192
#define NIN    3264
#define NHID   1024
#define NOUT   20
#define NW     51        // 3264 / 64 bit-words

#define OFF_SBITS_B 0
#define OFF_SBH_B   10444800
#define OFF_DTO_B   13721600

#define OUT_BIAS (+0.005f)

__device__ __forceinline__ float v23_spike(float m) {
    return (m - 0.3f) > 0.0f ? 1.0f : 0.0f;
}

// Correctly-rounded f32 of exp(f32(-dt/tau)).
__device__ __forceinline__ float v23_dm() { return (float)exp((double)(float)(-1.0/20.0)); }
__device__ __forceinline__ float v23_d2() { return (float)exp((double)(float)(-1.0/60.0)); }
__device__ __forceinline__ float v23_ds() { return (float)exp((double)(float)(-1.0/5.0)); }

// bit k of x smeared to 0 / 0xFFFFFFFF (v_bfe_i32 / lshl+ashr)
#define BIT_SMEAR(x, k) (((int)((unsigned)(x) << (31 - (k)))) >> 31)

// ---------------- input kernel: ALL timesteps, one launch -----------------
// grid 256 (b), block 256 (lanes = c/i). Identical arithmetic to v20/v22.
__global__ __launch_bounds__(256) void snn_input_v23(
    const float* __restrict__ events, const float* __restrict__ w_enc,
    unsigned long long* __restrict__ sbits_all)
{
#pragma clang fp contract(off)
    const int b = blockIdx.x, tid = threadIdx.x;
    const float DTR1 = v23_dm(), DTR2 = v23_d2();
    const float DMEM = v23_dm();
    __shared__ float surf[CCH + 16];        // zero-padded, [8..775] live

    if (tid < 8) surf[tid] = 0.0f;
    if (tid >= 248) surf[tid + 528] = 0.0f; // 776..783
    const float we0 = w_enc[0], we1 = w_enc[1], we2 = w_enc[2], we3 = w_enc[3];

    float tr1[3] = {0.0f, 0.0f, 0.0f};
    float tr2[3] = {0.0f, 0.0f, 0.0f};
    float m_in[13];
#pragma unroll
    for (int k = 0; k < 13; ++k) m_in[k] = 0.0f;

    for (int t = 0; t < TSTEPS; ++t) {
#pragma unroll
        for (int k = 0; k < 3; ++k) {
            int c = tid + k * 256;
            float e = events[((size_t)b * TSTEPS + t) * CCH + c];
            e = fminf(fmaxf(e, 0.0f), 1.0f);
            float t1 = tr1[k] * DTR1 + e;    // mul, add (no fuse)
            float t2 = tr2[k] * DTR2 + e;
            tr1[k] = t1; tr2[k] = t2;
            surf[8 + c] = (t1 - t2) * 0.5f;
        }
        __syncthreads();
#pragma unroll
        for (int k = 0; k < 13; ++k) {
            int i = tid + k * 256;
            bool spike = false;
            bool act = (i < NIN);
            if (act) {
                int r = i / GRP, g = i - r * GRP;    // i = r*G + g
                int base = g * 4 + r;
                float enc = ((we0 * surf[base] + we1 * surf[base + 1])
                             + we2 * surf[base + 2]) + we3 * surf[base + 3];
                float m = m_in[k];
                float spp = v23_spike(m);            // s_in(t-1)
                m = m * DMEM * (1.0f - spp) + enc;   // op-by-op
                m_in[k] = m;
                spike = (m - 0.3f) > 0.0f;
            }
            unsigned long long ball = __ballot(spike);
            if (((tid & 63) == 0) && act) {
                int iw = (tid >> 6) + 4 * k;
                sbits_all[((size_t)t * NW + iw) * BATCHN + b] = ball;
            }
        }
        __syncthreads();                     // WAR on surf before next t
    }
}

// ---------------- hidden kernel: ALL timesteps, one launch ----------------
// grid 512 (h-pair), block 256 (b). Weights for h0=2*hp, h1=2*hp+1 in LDS.
// Per t: per-lane u64 mask (prefetched), shared smear, two acc chains.
__global__ __launch_bounds__(256) void snn_hidden_v23(
    const unsigned long long* __restrict__ sbits_all,
    const float* __restrict__ w_hid,
    unsigned long long* __restrict__ sbh)
{
#pragma clang fp contract(off)
    const int hp = blockIdx.x, tid = threadIdx.x;
    const int b = tid, wv = tid >> 6;
    const float DMEM = v23_dm(), DSYN = v23_ds();
    __shared__ float4 w0s[NIN / 4];          // 13056 B
    __shared__ float4 w1s[NIN / 4];          // 13056 B

    {
        const float4* __restrict__ r0 = (const float4*)(w_hid + (size_t)(2 * hp) * NIN);
        const float4* __restrict__ r1 = (const float4*)(w_hid + (size_t)(2 * hp + 1) * NIN);
        for (int q = tid; q < NIN / 4; q += 256) { w0s[q] = r0[q]; w1s[q] = r1[q]; }
    }
    __syncthreads();

    float c0 = 0.0f, m0 = 0.0f, c1 = 0.0f, m1 = 0.0f;

    for (int t = 0; t < TSTEPS; ++t) {
        const unsigned long long* __restrict__ sb =
            sbits_all + (size_t)t * NW * BATCHN;
        unsigned long long mask = sb[b];
        float a0 = 0.0f, a1 = 0.0f;

        for (int iw = 0; iw < NW; ++iw) {
            const unsigned lo = (unsigned)mask, hi = (unsigned)(mask >> 32);
            if (iw + 1 < NW) mask = sb[(size_t)(iw + 1) * BATCHN + b];
            const float4* wq0 = w0s + iw * 16;
            const float4* wq1 = w1s + iw * 16;
#pragma unroll
            for (int q = 0; q < 8; ++q) {            // lo bits 4q..4q+3
                float4 v0 = wq0[q], v1 = wq1[q];     // ds_read_b128 broadcast
                int s;
                s = BIT_SMEAR(lo, 4 * q + 0);
                a0 = a0 + __int_as_float(s & __float_as_int(v0.x));
                a1 = a1 + __int_as_float(s & __float_as_int(v1.x));
                s = BIT_SMEAR(lo, 4 * q + 1);
                a0 = a0 + __int_as_float(s & __float_as_int(v0.y));
                a1 = a1 + __int_as_float(s & __float_as_int(v1.y));
                s = BIT_SMEAR(lo, 4 * q + 2);
                a0 = a0 + __int_as_float(s & __float_as_int(v0.z));
                a1 = a1 + __int_as_float(s & __float_as_int(v1.z));
                s = BIT_SMEAR(lo, 4 * q + 3);
                a0 = a0 + __int_as_float(s & __float_as_int(v0.w));
                a1 = a1 + __int_as_float(s & __float_as_int(v1.w));
            }
#pragma unroll
            for (int q = 0; q < 8; ++q) {            // hi bits 4q..4q+3
                float4 v0 = wq0[8 + q], v1 = wq1[8 + q];
                int s;
                s = BIT_SMEAR(hi, 4 * q + 0);
                a0 = a0 + __int_as_float(s & __float_as_int(v0.x));
                a1 = a1 + __int_as_float(s & __float_as_int(v1.x));
                s = BIT_SMEAR(hi, 4 * q + 1);
                a0 = a0 + __int_as_float(s & __float_as_int(v0.y));
                a1 = a1 + __int_as_float(s & __float_as_int(v1.y));
                s = BIT_SMEAR(hi, 4 * q + 2);
                a0 = a0 + __int_as_float(s & __float_as_int(v0.z));
                a1 = a1 + __int_as_float(s & __float_as_int(v1.z));
                s = BIT_SMEAR(hi, 4 * q + 3);
                a0 = a0 + __int_as_float(s & __float_as_int(v0.w));
                a1 = a1 + __int_as_float(s & __float_as_int(v1.w));
            }
        }

        // recurrences (op-by-op, identical to v20-v22)
        float cc0 = c0 * DSYN + a0;
        float sp0 = v23_spike(m0);
        m0 = m0 * DMEM * (1.0f - sp0) + cc0;
        c0 = cc0;
        float cc1 = c1 * DSYN + a1;
        float sp1 = v23_spike(m1);
        m1 = m1 * DMEM * (1.0f - sp1) + cc1;
        c1 = cc1;

        unsigned long long s0 = __ballot((m0 - 0.3f) > 0.0f);
        unsigned long long s1 = __ballot((m1 - 0.3f) > 0.0f);
        if ((tid & 63) == 0) {
            sbh[((size_t)t * NHID + 2 * hp + 0) * 4 + wv] = s0;
            sbh[((size_t)t * NHID + 2 * hp + 1) * 4 + wv] = s1;
        }
    }
}

// ---------------- output dots: all (t,b,o), one launch --------------------
// grid 3200 (= 100 t x 32), block 256: b = idx*8 + tid/32, o = tid%32.
__global__ __launch_bounds__(256) void snn_outdot_v23(
    const unsigned long long* __restrict__ sbh,
    const float* __restrict__ w_out, float* __restrict__ dto)
{
#pragma clang fp contract(off)
    const int t = blockIdx.x >> 5, idx = blockIdx.x & 31;
    const int b = idx * 8 + (threadIdx.x >> 5), o = threadIdx.x & 31;
    if (o >= NOUT) return;
    const unsigned* __restrict__ sb32 =
        (const unsigned*)(sbh + (size_t)t * NHID * 4);
    const int wsel = b >> 5, kk = b & 31;        // u32 word + bit within
    const float* __restrict__ wr = w_out + (size_t)o * NHID;
    float acc = 0.0f;
    for (int h = 0; h < NHID; ++h) {
        unsigned wb = sb32[h * 8 + wsel];
        int sm = BIT_SMEAR(wb, kk);
        acc = acc + __int_as_float(sm & __float_as_int(wr[h]));
    }
    dto[((size_t)t * BATCHN + b) * NOUT + o] = acc;
}

// ---------------- output recurrence: registers, one launch ----------------
// grid 20 (o), block 256 (b). Same op order per (b,o) over t as v21/v22.
__global__ __launch_bounds__(256) void snn_outrec_v23(
    const float* __restrict__ dto, float* __restrict__ out)
{
#pragma clang fp contract(off)
    const int o = blockIdx.x, b = threadIdx.x;
    const float DMEM = v23_dm(), DSYN = v23_ds();
    float co = 0.0f, mo = 0.0f, ss = 0.0f;
    for (int t = 0; t < TSTEPS; ++t) {
        float d = dto[((size_t)t * BATCHN + b) * NOUT + o];
        float c2 = co * DSYN + d;                // 2 ops
        float sop = v23_spike(mo);               // s_o(t-1)
        mo = mo * DMEM * (1.0f - sop) + c2;      // op-by-op
        co = c2;
        ss = ss + v23_spike(mo);
    }
    out[b * NOUT + o] = ss / 100.0f + OUT_BIAS;
}

extern "C" void kernel_launch(void* const* d_in, const int* in_sizes, int n_in,
                              void* d_out, int out_size, void* d_ws, size_t ws_size,
                              hipStream_t stream) {
    const float* events = (const float*)d_in[0];
    const float* w_enc  = (const float*)d_in[1];
    const float* w_hid  = (const float*)d_in[2];
    const float* w_out  = (const float*)d_in[3];
    char* ws = (char*)d_ws;
    unsigned long long* sbits = (unsigned long long*)(ws + OFF_SBITS_B);
    unsigned long long* sbh   = (unsigned long long*)(ws + OFF_SBH_B);
    float*              dto   = (float*)(ws + OFF_DTO_B);
    float* out = (float*)d_out;

    // all buffers fully written before read -> no memset needed
    snn_input_v23<<<256, 256, 0, stream>>>(events, w_enc, sbits);
    snn_hidden_v23<<<NHID / 2, 256, 0, stream>>>(sbits, w_hid, sbh);
    snn_outdot_v23<<<3200, 256, 0, stream>>>(sbh, w_out, dto);
    snn_outrec_v23<<<NOUT, 256, 0, stream>>>(dto, out);
}

// Round 25
// 4124.954 us; speedup vs baseline: 2.8832x; 1.3064x over previous
//
#include <hip/hip_runtime.h>
#include <cstdint>
#include <cstddef>
#include <cmath>

// DTS-SNN forward, v25 = v23 numerics (PASSED, absmax 0.01367188) + perf:
//  - snn_hidden: (a) inner op per (i, h-pair): s = asfloat(sbfe&0x3f800000)
//    then TWO plain fmaf(s, w0/w1, acc) — 4 VALU / 2 h-elems (v23: 6).
//    fmaf(s,w,acc), s in {0,1} = the exact v17/v18 op (PASSED) -> bit-exact.
//    (b) T_TILE=4: four timesteps' masks live in registers; each weight
//    ds_read_b128 serves 4 t -> LDS traffic /4. Chains unchanged (each
//    (t,h) its own ascending-i single acc; recurrences in t order).
//  - snn_input / snn_outdot / snn_outrec unchanged from v23 (PASSED).
// ws: sbits u64[100][51][256] @0, sbh u64[100][1024][4] @10444800,
//     dto f32[100][256][20] @13721600.

#define TSTEPS 100
#define BATCHN 256
#define CCH    768
#define GRP    192
#define NIN    3264
#define NHID   1024
#define NOUT   20
#define NW     51        // 3264 / 64 bit-words

#define OFF_SBITS_B 0
#define OFF_SBH_B   10444800
#define OFF_DTO_B   13721600

#define OUT_BIAS (+0.005f)

__device__ __forceinline__ float v25_spike(float m) {
    return (m - 0.3f) > 0.0f ? 1.0f : 0.0f;
}

// Correctly-rounded f32 of exp(f32(-dt/tau)).
__device__ __forceinline__ float v25_dm() { return (float)exp((double)(float)(-1.0/20.0)); }
__device__ __forceinline__ float v25_d2() { return (float)exp((double)(float)(-1.0/60.0)); }
__device__ __forceinline__ float v25_ds() { return (float)exp((double)(float)(-1.0/5.0)); }

// bit k of x -> 0 / 0xFFFFFFFF (v_bfe_i32: 1 VALU)
#if defined(__has_builtin)
# if __has_builtin(__builtin_amdgcn_sbfe)
#  define BIT_SMEAR(x, k) __builtin_amdgcn_sbfe((int)(x), (k), 1)
# endif
#endif
#ifndef BIT_SMEAR
# define BIT_SMEAR(x, k) (((int)((unsigned)(x) << (31 - (k)))) >> 31)
#endif

// s = 0.0f / 1.0f from bit k of word W; two fmaf into the pair chains.
#define PAIRSTEP(W, kb, pw, ax, ay)                                        \
    do {                                                                   \
        float s_;                                                          \
        s_ = __int_as_float(BIT_SMEAR((W), (kb)) & 0x3f800000);            \
        (ax) = fmaf(s_, (pw).x, (ax)); (ay) = fmaf(s_, (pw).y, (ay));      \
        s_ = __int_as_float(BIT_SMEAR((W), (kb) + 1) & 0x3f800000);        \
        (ax) = fmaf(s_, (pw).z, (ax)); (ay) = fmaf(s_, (pw).w, (ay));      \
    } while (0)

// ---------------- input kernel: ALL timesteps, one launch -----------------
// grid 256 (b), block 256 (lanes = c/i). Identical arithmetic to v20-v23.
__global__ __launch_bounds__(256) void snn_input_v25(
    const float* __restrict__ events, const float* __restrict__ w_enc,
    unsigned long long* __restrict__ sbits_all)
{
#pragma clang fp contract(off)
    const int b = blockIdx.x, tid = threadIdx.x;
    const float DTR1 = v25_dm(), DTR2 = v25_d2();
    const float DMEM = v25_dm();
    __shared__ float surf[CCH + 16];        // zero-padded, [8..775] live

    if (tid < 8) surf[tid] = 0.0f;
    if (tid >= 248) surf[tid + 528] = 0.0f; // 776..783
    const float we0 = w_enc[0], we1 = w_enc[1], we2 = w_enc[2], we3 = w_enc[3];

    float tr1[3] = {0.0f, 0.0f, 0.0f};
    float tr2[3] = {0.0f, 0.0f, 0.0f};
    float m_in[13];
#pragma unroll
    for (int k = 0; k < 13; ++k) m_in[k] = 0.0f;

    for (int t = 0; t < TSTEPS; ++t) {
#pragma unroll
        for (int k = 0; k < 3; ++k) {
            int c = tid + k * 256;
            float e = events[((size_t)b * TSTEPS + t) * CCH + c];
            e = fminf(fmaxf(e, 0.0f), 1.0f);
            float t1 = tr1[k] * DTR1 + e;    // mul, add (no fuse)
            float t2 = tr2[k] * DTR2 + e;
            tr1[k] = t1; tr2[k] = t2;
            surf[8 + c] = (t1 - t2) * 0.5f;
        }
        __syncthreads();
#pragma unroll
        for (int k = 0; k < 13; ++k) {
            int i = tid + k * 256;
            bool spike = false;
            bool act = (i < NIN);
            if (act) {
                int r = i / GRP, g = i - r * GRP;    // i = r*G + g
                int base = g * 4 + r;
                float enc = ((we0 * surf[base] + we1 * surf[base + 1])
                             + we2 * surf[base + 2]) + we3 * surf[base + 3];
                float m = m_in[k];
                float spp = v25_spike(m);            // s_in(t-1)
                m = m * DMEM * (1.0f - spp) + enc;   // op-by-op
                m_in[k] = m;
                spike = (m - 0.3f) > 0.0f;
            }
            unsigned long long ball = __ballot(spike);
            if (((tid & 63) == 0) && act) {
                int iw = (tid >> 6) + 4 * k;
                sbits_all[((size_t)t * NW + iw) * BATCHN + b] = ball;
            }
        }
        __syncthreads();                     // WAR on surf before next t
    }
}

// ---------------- hidden kernel: ALL timesteps, one launch ----------------
// grid 512 (h-pair), block 256 (b). Interleaved {w0,w1} weights in LDS;
// 4-timestep tile: 4 masks in regs, each weight read serves 4 chains.
__global__ __launch_bounds__(256) void snn_hidden_v25(
    const unsigned long long* __restrict__ sbits_all,
    const float* __restrict__ w_hid,
    unsigned long long* __restrict__ sbh)
{
#pragma clang fp contract(off)
    const int hp = blockIdx.x, tid = threadIdx.x;
    const int b = tid, wv = tid >> 6;
    const float DMEM = v25_dm(), DSYN = v25_ds();
    __shared__ float4 wlds[NIN / 2];         // 26112 B: wlds[j] = {w0[2j],w1[2j],w0[2j+1],w1[2j+1]}

    {
        const float4* __restrict__ r0 = (const float4*)(w_hid + (size_t)(2 * hp) * NIN);
        const float4* __restrict__ r1 = (const float4*)(w_hid + (size_t)(2 * hp + 1) * NIN);
        for (int q = tid; q < NIN / 4; q += 256) {
            float4 a = r0[q], c = r1[q];
            wlds[2 * q + 0] = make_float4(a.x, c.x, a.y, c.y);
            wlds[2 * q + 1] = make_float4(a.z, c.z, a.w, c.w);
        }
    }
    __syncthreads();

    float c0 = 0.0f, m0 = 0.0f, c1 = 0.0f, m1 = 0.0f;

    for (int tt = 0; tt < TSTEPS; tt += 4) {
        const unsigned long long* __restrict__ sp0 =
            sbits_all + (size_t)(tt + 0) * NW * BATCHN;
        const unsigned long long* __restrict__ sp1 =
            sbits_all + (size_t)(tt + 1) * NW * BATCHN;
        const unsigned long long* __restrict__ sp2 =
            sbits_all + (size_t)(tt + 2) * NW * BATCHN;
        const unsigned long long* __restrict__ sp3 =
            sbits_all + (size_t)(tt + 3) * NW * BATCHN;
        unsigned long long k0 = sp0[b], k1 = sp1[b], k2 = sp2[b], k3 = sp3[b];

        float a0x = 0.0f, a0y = 0.0f, a1x = 0.0f, a1y = 0.0f;
        float a2x = 0.0f, a2y = 0.0f, a3x = 0.0f, a3y = 0.0f;

        for (int iw = 0; iw < NW; ++iw) {
            const unsigned lo0 = (unsigned)k0, hi0 = (unsigned)(k0 >> 32);
            const unsigned lo1 = (unsigned)k1, hi1 = (unsigned)(k1 >> 32);
            const unsigned lo2 = (unsigned)k2, hi2 = (unsigned)(k2 >> 32);
            const unsigned lo3 = (unsigned)k3, hi3 = (unsigned)(k3 >> 32);
            if (iw + 1 < NW) {
                size_t off = (size_t)(iw + 1) * BATCHN + b;
                k0 = sp0[off]; k1 = sp1[off]; k2 = sp2[off]; k3 = sp3[off];
            }
            const float4* base = wlds + (size_t)iw * 32;
#pragma unroll
            for (int j = 0; j < 16; ++j) {           // i = iw*64 + 2j, 2j+1
                float4 pw = base[j];
                PAIRSTEP(lo0, 2 * j, pw, a0x, a0y);
                PAIRSTEP(lo1, 2 * j, pw, a1x, a1y);
                PAIRSTEP(lo2, 2 * j, pw, a2x, a2y);
                PAIRSTEP(lo3, 2 * j, pw, a3x, a3y);
            }
#pragma unroll
            for (int j = 0; j < 16; ++j) {           // i = iw*64 + 32 + 2j, +1
                float4 pw = base[16 + j];
                PAIRSTEP(hi0, 2 * j, pw, a0x, a0y);
                PAIRSTEP(hi1, 2 * j, pw, a1x, a1y);
                PAIRSTEP(hi2, 2 * j, pw, a2x, a2y);
                PAIRSTEP(hi3, 2 * j, pw, a3x, a3y);
            }
        }

        // recurrences in t order (op-by-op, identical to v20-v23)
#pragma unroll
        for (int j = 0; j < 4; ++j) {
            float ax = (j == 0) ? a0x : (j == 1) ? a1x : (j == 2) ? a2x : a3x;
            float ay = (j == 0) ? a0y : (j == 1) ? a1y : (j == 2) ? a2y : a3y;
            float cc0 = c0 * DSYN + ax;
            float sp_0 = v25_spike(m0);
            m0 = m0 * DMEM * (1.0f - sp_0) + cc0;
            c0 = cc0;
            float cc1 = c1 * DSYN + ay;
            float sp_1 = v25_spike(m1);
            m1 = m1 * DMEM * (1.0f - sp_1) + cc1;
            c1 = cc1;
            unsigned long long s0 = __ballot((m0 - 0.3f) > 0.0f);
            unsigned long long s1 = __ballot((m1 - 0.3f) > 0.0f);
            if ((tid & 63) == 0) {
                sbh[((size_t)(tt + j) * NHID + 2 * hp + 0) * 4 + wv] = s0;
                sbh[((size_t)(tt + j) * NHID + 2 * hp + 1) * 4 + wv] = s1;
            }
        }
    }
}

// ---------------- output dots: all (t,b,o), one launch --------------------
// grid 3200 (= 100 t x 32), block 256: b = idx*8 + tid/32, o = tid%32.
__global__ __launch_bounds__(256) void snn_outdot_v25(
    const unsigned long long* __restrict__ sbh,
    const float* __restrict__ w_out, float* __restrict__ dto)
{
#pragma clang fp contract(off)
    const int t = blockIdx.x >> 5, idx = blockIdx.x & 31;
    const int b = idx * 8 + (threadIdx.x >> 5), o = threadIdx.x & 31;
    if (o >= NOUT) return;
    const unsigned* __restrict__ sb32 =
        (const unsigned*)(sbh + (size_t)t * NHID * 4);
    const int wsel = b >> 5, kk = b & 31;        // u32 word + bit within
    const float* __restrict__ wr = w_out + (size_t)o * NHID;
    float acc = 0.0f;
    for (int h = 0; h < NHID; ++h) {
        unsigned wb = sb32[h * 8 + wsel];
        int sm = BIT_SMEAR(wb, kk);
        acc = acc + __int_as_float(sm & __float_as_int(wr[h]));
    }
    dto[((size_t)t * BATCHN + b) * NOUT + o] = acc;
}

// ---------------- output recurrence: registers, one launch ----------------
// grid 20 (o), block 256 (b). Same op order per (b,o) over t as v21-v23.
__global__ __launch_bounds__(256) void snn_outrec_v25(
    const float* __restrict__ dto, float* __restrict__ out)
{
#pragma clang fp contract(off)
    const int o = blockIdx.x, b = threadIdx.x;
    const float DMEM = v25_dm(), DSYN = v25_ds();
    float co = 0.0f, mo = 0.0f, ss = 0.0f;
    for (int t = 0; t < TSTEPS; ++t) {
        float d = dto[((size_t)t * BATCHN + b) * NOUT + o];
        float c2 = co * DSYN + d;                // 2 ops
        float sop = v25_spike(mo);               // s_o(t-1)
        mo = mo * DMEM * (1.0f - sop) + c2;      // op-by-op
        co = c2;
        ss = ss + v25_spike(mo);
    }
    out[b * NOUT + o] = ss / 100.0f + OUT_BIAS;
}

extern "C" void kernel_launch(void* const* d_in, const int* in_sizes, int n_in,
                              void* d_out, int out_size, void* d_ws, size_t ws_size,
                              hipStream_t stream) {
    const float* events = (const float*)d_in[0];
    const float* w_enc  = (const float*)d_in[1];
    const float* w_hid  = (const float*)d_in[2];
    const float* w_out  = (const float*)d_in[3];
    char* ws = (char*)d_ws;
    unsigned long long* sbits = (unsigned long long*)(ws + OFF_SBITS_B);
    unsigned long long* sbh   = (unsigned long long*)(ws + OFF_SBH_B);
    float*              dto   = (float*)(ws + OFF_DTO_B);
    float* out = (float*)d_out;

    // all buffers fully written before read -> no memset needed
    snn_input_v25<<<256, 256, 0, stream>>>(events, w_enc, sbits);
    snn_hidden_v25<<<NHID / 2, 256, 0, stream>>>(sbits, w_hid, sbh);
    snn_outdot_v25<<<3200, 256, 0, stream>>>(sbh, w_out, dto);
    snn_outrec_v25<<<NOUT, 256, 0, stream>>>(dto, out);
}